// Round 12
// baseline (127.349 us; speedup 1.0000x reference)
//
#include <hip/hip_runtime.h>

// Causal attention, fp32 in/out, B=8 S=2048 D=64, NO 1/sqrt(d) scaling.
// R12 = R10 frame (2 dispatches, fragment-major V, 512x256, triangle pairing)
// with the chunk loop restructured for ONE L2-wait per chunk:
//   issue all 32 K-frag loads -> all 48 QK MFMAs -> issue 16 V loads ->
//   mask -> softmax (V latency hides here) -> PV from registers.
// R10's gp-pair structure waited on L2 4x per chunk with only ~12 MFMAs of
// cover each. VGPR budget: grid caps residency at 2 waves/SIMD, so up to
// 256 VGPRs are free (R9/R11 evidence: extra waves/block only add barrier
// tail; R7 evidence: (x,4) bounds force spill — keep natural allocation).
// Fragment layouts (verified R2):
//   A[m][k]: m=lane&15, k=quad*8+j | B[k][n]: n=lane&15, k=quad*8+j
//   C/D:     col=lane&15, row=quad*4+reg
// Vf layout: chunk c(32 keys), dim-group nt: lane l holds
//   V[b][c*32+(l>>4)*8+j][nt*16+(l&15)], j=0..7 (16B, consecutive by lane).

#define BATCH 8
#define SEQ 2048
#define DIM 64
#define NEL (BATCH * SEQ * DIM)

typedef __attribute__((ext_vector_type(8))) short short8;
typedef __attribute__((ext_vector_type(4))) float f32x4;

#define MFMA(a, b, c) __builtin_amdgcn_mfma_f32_16x16x32_bf16(a, b, c, 0, 0, 0)

__device__ __forceinline__ unsigned short f2bf(float x) {
    unsigned u = __float_as_uint(x);
    unsigned r = u + 0x7fffu + ((u >> 16) & 1u);   // RNE
    return (unsigned short)(r >> 16);
}
__device__ __forceinline__ float bf2f(unsigned short h) {
    return __uint_as_float(((unsigned)h) << 16);
}
__device__ __forceinline__ short8 ld8(const unsigned short* p) {
    return *(const short8*)p;
}

__device__ __forceinline__ float dpp_max16(float x) {
    float o;
    o = __int_as_float(__builtin_amdgcn_update_dpp(0, __float_as_int(x), 0xB1, 0xF, 0xF, true));
    x = fmaxf(x, o);
    o = __int_as_float(__builtin_amdgcn_update_dpp(0, __float_as_int(x), 0x4E, 0xF, 0xF, true));
    x = fmaxf(x, o);
    o = __int_as_float(__builtin_amdgcn_update_dpp(0, __float_as_int(x), 0x141, 0xF, 0xF, true));
    x = fmaxf(x, o);
    o = __int_as_float(__builtin_amdgcn_update_dpp(0, __float_as_int(x), 0x140, 0xF, 0xF, true));
    return fmaxf(x, o);
}
__device__ __forceinline__ float dpp_sum16(float x) {
    float o;
    o = __int_as_float(__builtin_amdgcn_update_dpp(0, __float_as_int(x), 0xB1, 0xF, 0xF, true));
    x += o;
    o = __int_as_float(__builtin_amdgcn_update_dpp(0, __float_as_int(x), 0x4E, 0xF, 0xF, true));
    x += o;
    o = __int_as_float(__builtin_amdgcn_update_dpp(0, __float_as_int(x), 0x141, 0xF, 0xF, true));
    x += o;
    o = __int_as_float(__builtin_amdgcn_update_dpp(0, __float_as_int(x), 0x140, 0xF, 0xF, true));
    return x + o;
}

// ---- pre-pass: Q/K hi-lo split convert + V fragment-major bf16 ----
__global__ __launch_bounds__(256) void prep(
    const float* __restrict__ Q, const float* __restrict__ K,
    const float* __restrict__ V,
    unsigned short* __restrict__ Qh, unsigned short* __restrict__ Ql,
    unsigned short* __restrict__ Kh, unsigned short* __restrict__ Kl,
    unsigned short* __restrict__ Vf)
{
    __shared__ unsigned short sT[64][72];   // [dim][key] for one 64-key tile
    const int blk = blockIdx.x;
    const int t = threadIdx.x;

    if (blk < 2048) {
        const int idx = (blk * 256 + t) * 4;
        const float* src; unsigned short *dh, *dl; int off;
        if (idx < NEL) { src = Q; dh = Qh; dl = Ql; off = idx; }
        else           { src = K; dh = Kh; dl = Kl; off = idx - NEL; }
        float4 v = *(const float4*)(src + off);
        ushort4 h, l;
        h.x = f2bf(v.x); l.x = f2bf(v.x - bf2f(h.x));
        h.y = f2bf(v.y); l.y = f2bf(v.y - bf2f(h.y));
        h.z = f2bf(v.z); l.z = f2bf(v.z - bf2f(h.z));
        h.w = f2bf(v.w); l.w = f2bf(v.w - bf2f(h.w));
        *(ushort4*)(dh + off) = h;
        *(ushort4*)(dl + off) = l;
        return;
    }

    const int tile = blk - 2048;            // 8 batches * 32 tiles of 64 keys
    const int b = tile >> 5;
    const int s0 = (tile & 31) * 64;
    const int srow = t >> 4;
    const int d4   = (t & 15) * 4;
#pragma unroll
    for (int i = 0; i < 4; ++i) {
        const int row = srow + i * 16;      // key within tile
        float4 v = *(const float4*)(V + ((size_t)(b * SEQ + s0 + row)) * DIM + d4);
        sT[d4 + 0][row] = f2bf(v.x);
        sT[d4 + 1][row] = f2bf(v.y);
        sT[d4 + 2][row] = f2bf(v.z);
        sT[d4 + 3][row] = f2bf(v.w);
    }
    __syncthreads();
    // write 2 chunks x 4 nt x 64 lanes fragments (16B each); 2 per thread
#pragma unroll
    for (int i = 0; i < 2; ++i) {
        const int fid = t + i * 256;        // 0..511
        const int cc  = fid >> 8;           // chunk within tile (0..1)
        const int nt  = (fid >> 6) & 3;     // dim group
        const int l   = fid & 63;           // lane
        const int key = cc * 32 + (l >> 4) * 8;
        const int dim = nt * 16 + (l & 15);
        const int c   = (s0 >> 5) + cc;     // global 32-key chunk (0..63)
        unsigned short* dst =
            Vf + ((((size_t)(b * 64 + c)) * 4 + nt) << 9) + l * 8;
        *(float4*)dst = *(const float4*)&sT[dim][key];
    }
}

// ---- main: 512 blocks x 256 threads (4 waves), q-tiles {pair, 127-pair} ----
__global__ __launch_bounds__(256) void attn_main(
    const unsigned short* __restrict__ Qh, const unsigned short* __restrict__ Ql,
    const unsigned short* __restrict__ Kh, const unsigned short* __restrict__ Kl,
    const unsigned short* __restrict__ Vf, float* __restrict__ O)
{
    // per-wave union scratch: sP (ushort[16][136]) == sO (float[16][68]) = 4352B
    __shared__ __align__(16) char scratch[4][4352];
    __shared__ float sMl[4][16][2];

    const int bid  = blockIdx.x;
    const int b    = bid & (BATCH - 1);
    const int pair = bid >> 3;              // 0..63

    const int t    = threadIdx.x;
    const int w    = t >> 6;
    const int lane = t & 63;
    const int quad = lane >> 4;
    const int n16  = lane & 15;
    const int boff = b * SEQ;

    unsigned short* sPw = (unsigned short*)scratch[w];   // [16][136]
    float*          sOw = (float*)scratch[w];            // [16][68]

    for (int half = 0; half < 2; ++half) {
        const int qt = half ? (127 - pair) : pair;
        const int q0 = qt * 16;
        const int q_max = q0 + 15;

        const unsigned short* qp  = Qh + ((size_t)(boff + q0 + n16)) * DIM + quad * 8;
        const unsigned short* qlp = Ql + ((size_t)(boff + q0 + n16)) * DIM + quad * 8;
        short8 qh0 = ld8(qp),  qh1 = ld8(qp + 32);
        short8 ql0 = ld8(qlp), ql1 = ld8(qlp + 32);

        float m0 = -1e30f, m1 = -1e30f, m2 = -1e30f, m3 = -1e30f;
        float l0 = 0.f, l1 = 0.f, l2 = 0.f, l3 = 0.f;
        f32x4 oacc[4];
#pragma unroll
        for (int i = 0; i < 4; ++i) oacc[i] = (f32x4){0.f, 0.f, 0.f, 0.f};

        for (int kb = w * 128; kb <= q_max; kb += 512) {
            const int rem  = q_max - kb;
            const int nsub = min(8, (rem >> 4) + 1);
            const int nchain = (nsub + 1) >> 1;

            // ---- ALL 32 K-frag loads first: one L2-wait per chunk ----
            short8 kh0[8], kh1[8], kl0[8], kl1[8];
#pragma unroll
            for (int st = 0; st < 8; ++st) {
                if (st < nsub) {
                    const size_t kr = (size_t)(boff + kb + st * 16 + n16) * DIM + quad * 8;
                    kh0[st] = ld8(Kh + kr); kh1[st] = ld8(Kh + kr + 32);
                    kl0[st] = ld8(Kl + kr); kl1[st] = ld8(Kl + kr + 32);
                }
            }

            // ---- all QK^T MFMAs (K regs die here) ----
            f32x4 sacc[8];
#pragma unroll
            for (int st = 0; st < 8; ++st) {
                if (st < nsub) {
                    f32x4 acc = (f32x4){0.f, 0.f, 0.f, 0.f};
                    acc = MFMA(qh0, kh0[st], acc);
                    acc = MFMA(qh1, kh1[st], acc);
                    acc = MFMA(qh0, kl0[st], acc);
                    acc = MFMA(qh1, kl1[st], acc);
                    acc = MFMA(ql0, kh0[st], acc);
                    acc = MFMA(ql1, kh1[st], acc);
                    sacc[st] = acc;
                } else {
                    sacc[st] = (f32x4){-1e30f, -1e30f, -1e30f, -1e30f};
                }
            }

            // ---- V loads now; latency hides behind mask+softmax ----
            short8 vf[4][4];
#pragma unroll
            for (int ch = 0; ch < 4; ++ch) {
                if (ch < nchain) {
                    const size_t cbase =
                        (((size_t)(b * 64 + (kb >> 5) + ch)) * 4) << 9;
#pragma unroll
                    for (int nt = 0; nt < 4; ++nt)
                        vf[ch][nt] = ld8(Vf + cbase + (nt << 9) + lane * 8);
                }
            }

            // ---- causal mask: any chunk overlapping any query row ----
            if (kb + 127 > q0) {
#pragma unroll
                for (int st = 0; st < 8; ++st) {
                    if (st < nsub) {
                        const int key = kb + st * 16 + n16;
#pragma unroll
                        for (int r = 0; r < 4; ++r)
                            if (key > q0 + quad * 4 + r) sacc[st][r] = -1e30f;
                    }
                }
            }

            // ---- online softmax over 128 keys (DPP reductions) ----
            float mt0 = sacc[0][0], mt1 = sacc[0][1], mt2 = sacc[0][2], mt3 = sacc[0][3];
#pragma unroll
            for (int st = 1; st < 8; ++st) {
                mt0 = fmaxf(mt0, sacc[st][0]);
                mt1 = fmaxf(mt1, sacc[st][1]);
                mt2 = fmaxf(mt2, sacc[st][2]);
                mt3 = fmaxf(mt3, sacc[st][3]);
            }
            mt0 = dpp_max16(mt0); mt1 = dpp_max16(mt1);
            mt2 = dpp_max16(mt2); mt3 = dpp_max16(mt3);
            const float mn0 = fmaxf(m0, mt0), mn1 = fmaxf(m1, mt1);
            const float mn2 = fmaxf(m2, mt2), mn3 = fmaxf(m3, mt3);
            const float a0 = __expf(m0 - mn0), a1 = __expf(m1 - mn1);
            const float a2 = __expf(m2 - mn2), a3 = __expf(m3 - mn3);
            m0 = mn0; m1 = mn1; m2 = mn2; m3 = mn3;

            float ps0 = 0.f, ps1 = 0.f, ps2 = 0.f, ps3 = 0.f;
            const int stmax = 2 * nchain;
#pragma unroll
            for (int st = 0; st < 8; ++st) {
                if (st < stmax) {
                    float p0 = 0.f, p1 = 0.f, p2 = 0.f, p3 = 0.f;
                    if (st < nsub) {
                        p0 = __expf(sacc[st][0] - mn0);
                        p1 = __expf(sacc[st][1] - mn1);
                        p2 = __expf(sacc[st][2] - mn2);
                        p3 = __expf(sacc[st][3] - mn3);
                        ps0 += p0; ps1 += p1; ps2 += p2; ps3 += p3;
                    }
                    const int col = st * 16 + n16;
                    sPw[(quad * 4 + 0) * 136 + col] = f2bf(p0);
                    sPw[(quad * 4 + 1) * 136 + col] = f2bf(p1);
                    sPw[(quad * 4 + 2) * 136 + col] = f2bf(p2);
                    sPw[(quad * 4 + 3) * 136 + col] = f2bf(p3);
                }
            }
            ps0 = dpp_sum16(ps0); ps1 = dpp_sum16(ps1);
            ps2 = dpp_sum16(ps2); ps3 = dpp_sum16(ps3);
            l0 = l0 * a0 + ps0; l1 = l1 * a1 + ps1;
            l2 = l2 * a2 + ps2; l3 = l3 * a3 + ps3;
#pragma unroll
            for (int nt = 0; nt < 4; ++nt) {
                oacc[nt][0] *= a0; oacc[nt][1] *= a1;
                oacc[nt][2] *= a2; oacc[nt][3] *= a3;
            }

            // ---- PV: P via same-wave LDS; V already in registers ----
#pragma unroll
            for (int ch = 0; ch < 4; ++ch) {
                if (ch < nchain) {
                    short8 pa = ld8(&sPw[n16 * 136 + ch * 32 + quad * 8]);
#pragma unroll
                    for (int nt = 0; nt < 4; ++nt)
                        oacc[nt] = MFMA(pa, vf[ch][nt], oacc[nt]);
                }
            }
        }

        // ---- flash-combine the 4 waves' partials (sO overlays sP) ----
#pragma unroll
        for (int nt = 0; nt < 4; ++nt)
#pragma unroll
            for (int r = 0; r < 4; ++r)
                sOw[(quad * 4 + r) * 68 + nt * 16 + n16] = oacc[nt][r];
        if (n16 == 0) {
            sMl[w][quad * 4 + 0][0] = m0; sMl[w][quad * 4 + 0][1] = l0;
            sMl[w][quad * 4 + 1][0] = m1; sMl[w][quad * 4 + 1][1] = l1;
            sMl[w][quad * 4 + 2][0] = m2; sMl[w][quad * 4 + 2][1] = l2;
            sMl[w][quad * 4 + 3][0] = m3; sMl[w][quad * 4 + 3][1] = l3;
        }
        __syncthreads();

        const int row  = t >> 4;
        const int col4 = (t & 15) * 4;
        float M = fmaxf(fmaxf(sMl[0][row][0], sMl[1][row][0]),
                        fmaxf(sMl[2][row][0], sMl[3][row][0]));
        float L = 0.f;
        float ox = 0.f, oy = 0.f, oz = 0.f, ow = 0.f;
#pragma unroll
        for (int wv = 0; wv < 4; ++wv) {
            const float ew = __expf(sMl[wv][row][0] - M);
            L += ew * sMl[wv][row][1];
            const float* op = (const float*)scratch[wv] + row * 68 + col4;
            ox += ew * op[0]; oy += ew * op[1]; oz += ew * op[2]; ow += ew * op[3];
        }
        const float inv = 1.0f / L;
        float4 res = make_float4(ox * inv, oy * inv, oz * inv, ow * inv);
        *(float4*)(O + ((size_t)(boff + q0 + row)) * DIM + col4) = res;

        __syncthreads();   // scratch reused as sP by the next half
    }
}

extern "C" void kernel_launch(void* const* d_in, const int* in_sizes, int n_in,
                              void* d_out, int out_size, void* d_ws, size_t ws_size,
                              hipStream_t stream) {
    const float* q = (const float*)d_in[0];
    const float* k = (const float*)d_in[1];
    const float* v = (const float*)d_in[2];
    float* out = (float*)d_out;

    unsigned short* Qh = (unsigned short*)d_ws;
    unsigned short* Ql = Qh + NEL;
    unsigned short* Kh = Ql + NEL;
    unsigned short* Kl = Kh + NEL;
    unsigned short* Vf = Kl + NEL;   // 10 MB total in d_ws

    prep<<<dim3(2048 + 256), dim3(256), 0, stream>>>(q, k, v, Qh, Ql, Kh, Kl, Vf);
    attn_main<<<dim3(512), dim3(256), 0, stream>>>(Qh, Ql, Kh, Kl, Vf, out);
}

// Round 13
// 115.934 us; speedup vs baseline: 1.0985x; 1.0985x over previous
//
#include <hip/hip_runtime.h>

// Causal attention, fp32 in/out, B=8 S=2048 D=64, NO 1/sqrt(d) scaling.
// R13 = R10 frame + prefix-sharing: block pair {L=j, H=127-j} processed in
// ONE loop over H's chunks. L's key range is a prefix of H's, so L's QK/PV
// reuse H's loaded K/V fragments -> L's loads vanish (traffic 8704->6400
// units, -26%) and per-wave critical path ~5 -> ~3.5 chunk-iterations.
// MFMA pipe is 7% busy; the extra light-tile MFMAs are free.
// Block weight = chunks(H) in 9..16 (imbalance): j = jj<32? jj : 95-jj maps
// bids c and c+256 (likely RR co-residents) to complementary weights, heavy
// dispatched first. Load structure stays R10's gp-pairs (R12 proved hoisting
// regresses). V frags loaded once per chunk, shared by both tiles.
// Fragment layouts (verified R2):
//   A[m][k]: m=lane&15, k=quad*8+j | B[k][n]: n=lane&15, k=quad*8+j
//   C/D:     col=lane&15, row=quad*4+reg
// Vf layout: chunk c(32 keys), dim-group nt: lane l holds
//   V[b][c*32+(l>>4)*8+jj][nt*16+(l&15)], jj=0..7 (16B, consecutive by lane).

#define BATCH 8
#define SEQ 2048
#define DIM 64
#define NEL (BATCH * SEQ * DIM)

typedef __attribute__((ext_vector_type(8))) short short8;
typedef __attribute__((ext_vector_type(4))) float f32x4;

#define MFMA(a, b, c) __builtin_amdgcn_mfma_f32_16x16x32_bf16(a, b, c, 0, 0, 0)

__device__ __forceinline__ unsigned short f2bf(float x) {
    unsigned u = __float_as_uint(x);
    unsigned r = u + 0x7fffu + ((u >> 16) & 1u);   // RNE
    return (unsigned short)(r >> 16);
}
__device__ __forceinline__ float bf2f(unsigned short h) {
    return __uint_as_float(((unsigned)h) << 16);
}
__device__ __forceinline__ short8 ld8(const unsigned short* p) {
    return *(const short8*)p;
}

__device__ __forceinline__ float dpp_max16(float x) {
    float o;
    o = __int_as_float(__builtin_amdgcn_update_dpp(0, __float_as_int(x), 0xB1, 0xF, 0xF, true));
    x = fmaxf(x, o);
    o = __int_as_float(__builtin_amdgcn_update_dpp(0, __float_as_int(x), 0x4E, 0xF, 0xF, true));
    x = fmaxf(x, o);
    o = __int_as_float(__builtin_amdgcn_update_dpp(0, __float_as_int(x), 0x141, 0xF, 0xF, true));
    x = fmaxf(x, o);
    o = __int_as_float(__builtin_amdgcn_update_dpp(0, __float_as_int(x), 0x140, 0xF, 0xF, true));
    return fmaxf(x, o);
}
__device__ __forceinline__ float dpp_sum16(float x) {
    float o;
    o = __int_as_float(__builtin_amdgcn_update_dpp(0, __float_as_int(x), 0xB1, 0xF, 0xF, true));
    x += o;
    o = __int_as_float(__builtin_amdgcn_update_dpp(0, __float_as_int(x), 0x4E, 0xF, 0xF, true));
    x += o;
    o = __int_as_float(__builtin_amdgcn_update_dpp(0, __float_as_int(x), 0x141, 0xF, 0xF, true));
    x += o;
    o = __int_as_float(__builtin_amdgcn_update_dpp(0, __float_as_int(x), 0x140, 0xF, 0xF, true));
    return x + o;
}

// ---- pre-pass: Q/K hi-lo split convert + V fragment-major bf16 ----
__global__ __launch_bounds__(256) void prep(
    const float* __restrict__ Q, const float* __restrict__ K,
    const float* __restrict__ V,
    unsigned short* __restrict__ Qh, unsigned short* __restrict__ Ql,
    unsigned short* __restrict__ Kh, unsigned short* __restrict__ Kl,
    unsigned short* __restrict__ Vf)
{
    __shared__ unsigned short sT[64][72];   // [dim][key] for one 64-key tile
    const int blk = blockIdx.x;
    const int t = threadIdx.x;

    if (blk < 2048) {
        const int idx = (blk * 256 + t) * 4;
        const float* src; unsigned short *dh, *dl; int off;
        if (idx < NEL) { src = Q; dh = Qh; dl = Ql; off = idx; }
        else           { src = K; dh = Kh; dl = Kl; off = idx - NEL; }
        float4 v = *(const float4*)(src + off);
        ushort4 h, l;
        h.x = f2bf(v.x); l.x = f2bf(v.x - bf2f(h.x));
        h.y = f2bf(v.y); l.y = f2bf(v.y - bf2f(h.y));
        h.z = f2bf(v.z); l.z = f2bf(v.z - bf2f(h.z));
        h.w = f2bf(v.w); l.w = f2bf(v.w - bf2f(h.w));
        *(ushort4*)(dh + off) = h;
        *(ushort4*)(dl + off) = l;
        return;
    }

    const int tile = blk - 2048;            // 8 batches * 32 tiles of 64 keys
    const int b = tile >> 5;
    const int s0 = (tile & 31) * 64;
    const int srow = t >> 4;
    const int d4   = (t & 15) * 4;
#pragma unroll
    for (int i = 0; i < 4; ++i) {
        const int row = srow + i * 16;
        float4 v = *(const float4*)(V + ((size_t)(b * SEQ + s0 + row)) * DIM + d4);
        sT[d4 + 0][row] = f2bf(v.x);
        sT[d4 + 1][row] = f2bf(v.y);
        sT[d4 + 2][row] = f2bf(v.z);
        sT[d4 + 3][row] = f2bf(v.w);
    }
    __syncthreads();
#pragma unroll
    for (int i = 0; i < 2; ++i) {
        const int fid = t + i * 256;
        const int cc  = fid >> 8;
        const int nt  = (fid >> 6) & 3;
        const int l   = fid & 63;
        const int key = cc * 32 + (l >> 4) * 8;
        const int dim = nt * 16 + (l & 15);
        const int c   = (s0 >> 5) + cc;
        unsigned short* dst =
            Vf + ((((size_t)(b * 64 + c)) * 4 + nt) << 9) + l * 8;
        *(float4*)dst = *(const float4*)&sT[dim][key];
    }
}

// ---- main: 512 blocks x 256 threads; prefix-shared pair {j, 127-j} ----
__global__ __launch_bounds__(256) void attn_main(
    const unsigned short* __restrict__ Qh, const unsigned short* __restrict__ Ql,
    const unsigned short* __restrict__ Kh, const unsigned short* __restrict__ Kl,
    const unsigned short* __restrict__ Vf, float* __restrict__ O)
{
    // scratch: per-wave sP_H (ushort[16][136]) == sO (float[16][68]) = 4352B
    // sPL: per-wave sP for the light tile.
    __shared__ __align__(16) char scratch[4][4352];
    __shared__ __align__(16) unsigned short sPL[4][16][136];
    __shared__ float sMl[4][16][2];

    const int bid = blockIdx.x;
    const int b   = bid & (BATCH - 1);
    const int jj  = bid >> 3;                       // 0..63
    const int j   = (jj < 32) ? jj : 95 - jj;       // anti-correlated weights
    const int q0L = j * 16,        q_maxL = q0L + 15;
    const int q0H = (127 - j) * 16, q_maxH = q0H + 15;

    const int t    = threadIdx.x;
    const int w    = t >> 6;
    const int lane = t & 63;
    const int quad = lane >> 4;
    const int n16  = lane & 15;
    const int boff = b * SEQ;

    unsigned short* sPw = (unsigned short*)scratch[w];   // [16][136] (H)
    float*          sOw = (float*)scratch[w];            // [16][68]
    unsigned short* sPLw = &sPL[w][0][0];

    // ---- Q fragments for both tiles ----
    const unsigned short* qpL  = Qh + ((size_t)(boff + q0L + n16)) * DIM + quad * 8;
    const unsigned short* qlpL = Ql + ((size_t)(boff + q0L + n16)) * DIM + quad * 8;
    short8 qh0L = ld8(qpL),  qh1L = ld8(qpL + 32);
    short8 ql0L = ld8(qlpL), ql1L = ld8(qlpL + 32);
    const unsigned short* qpH  = Qh + ((size_t)(boff + q0H + n16)) * DIM + quad * 8;
    const unsigned short* qlpH = Ql + ((size_t)(boff + q0H + n16)) * DIM + quad * 8;
    short8 qh0H = ld8(qpH),  qh1H = ld8(qpH + 32);
    short8 ql0H = ld8(qlpH), ql1H = ld8(qlpH + 32);

    float mL0 = -1e30f, mL1 = -1e30f, mL2 = -1e30f, mL3 = -1e30f;
    float lL0 = 0.f, lL1 = 0.f, lL2 = 0.f, lL3 = 0.f;
    float mH0 = -1e30f, mH1 = -1e30f, mH2 = -1e30f, mH3 = -1e30f;
    float lH0 = 0.f, lH1 = 0.f, lH2 = 0.f, lH3 = 0.f;
    f32x4 oL[4], oH[4];
#pragma unroll
    for (int i = 0; i < 4; ++i) {
        oL[i] = (f32x4){0.f, 0.f, 0.f, 0.f};
        oH[i] = (f32x4){0.f, 0.f, 0.f, 0.f};
    }

    for (int kb = w * 128; kb <= q_maxH; kb += 512) {
        const int nsubH   = min(8, ((q_maxH - kb) >> 4) + 1);
        const int nchainH = (nsubH + 1) >> 1;
        const bool lact   = (kb <= q_maxL);
        const int nsubL   = lact ? min(8, ((q_maxL - kb) >> 4) + 1) : 0;
        const int nchainL = (nsubL + 1) >> 1;

        f32x4 sH[8], sL[8];

        // ---- QK^T: gp-pairs (R10 structure); frags feed H and (prefix) L ----
#pragma unroll
        for (int gp = 0; gp < 4; ++gp) {
            const int stA = 2 * gp, stB = stA + 1;
            if (stA < nsubH) {
                const size_t krA = (size_t)(boff + kb + stA * 16 + n16) * DIM + quad * 8;
                short8 khA0 = ld8(Kh + krA), khA1 = ld8(Kh + krA + 32);
                short8 klA0 = ld8(Kl + krA), klA1 = ld8(Kl + krA + 32);
                const bool okB = (stB < nsubH);
                const size_t krB = (size_t)(boff + kb + stB * 16 + n16) * DIM + quad * 8;
                short8 khB0, khB1, klB0, klB1;
                if (okB) {
                    khB0 = ld8(Kh + krB); khB1 = ld8(Kh + krB + 32);
                    klB0 = ld8(Kl + krB); klB1 = ld8(Kl + krB + 32);
                }
                {
                    f32x4 acc = (f32x4){0.f, 0.f, 0.f, 0.f};
                    acc = MFMA(qh0H, khA0, acc);
                    acc = MFMA(qh1H, khA1, acc);
                    acc = MFMA(qh0H, klA0, acc);
                    acc = MFMA(qh1H, klA1, acc);
                    acc = MFMA(ql0H, khA0, acc);
                    acc = MFMA(ql1H, khA1, acc);
                    sH[stA] = acc;
                }
                if (stA < nsubL) {
                    f32x4 acc = (f32x4){0.f, 0.f, 0.f, 0.f};
                    acc = MFMA(qh0L, khA0, acc);
                    acc = MFMA(qh1L, khA1, acc);
                    acc = MFMA(qh0L, klA0, acc);
                    acc = MFMA(qh1L, klA1, acc);
                    acc = MFMA(ql0L, khA0, acc);
                    acc = MFMA(ql1L, khA1, acc);
                    sL[stA] = acc;
                } else {
                    sL[stA] = (f32x4){-1e30f, -1e30f, -1e30f, -1e30f};
                }
                if (okB) {
                    f32x4 acc = (f32x4){0.f, 0.f, 0.f, 0.f};
                    acc = MFMA(qh0H, khB0, acc);
                    acc = MFMA(qh1H, khB1, acc);
                    acc = MFMA(qh0H, klB0, acc);
                    acc = MFMA(qh1H, klB1, acc);
                    acc = MFMA(ql0H, khB0, acc);
                    acc = MFMA(ql1H, khB1, acc);
                    sH[stB] = acc;
                    if (stB < nsubL) {
                        f32x4 acc2 = (f32x4){0.f, 0.f, 0.f, 0.f};
                        acc2 = MFMA(qh0L, khB0, acc2);
                        acc2 = MFMA(qh1L, khB1, acc2);
                        acc2 = MFMA(qh0L, klB0, acc2);
                        acc2 = MFMA(qh1L, klB1, acc2);
                        acc2 = MFMA(ql0L, khB0, acc2);
                        acc2 = MFMA(ql1L, khB1, acc2);
                        sL[stB] = acc2;
                    } else {
                        sL[stB] = (f32x4){-1e30f, -1e30f, -1e30f, -1e30f};
                    }
                } else {
                    sH[stB] = (f32x4){-1e30f, -1e30f, -1e30f, -1e30f};
                    sL[stB] = (f32x4){-1e30f, -1e30f, -1e30f, -1e30f};
                }
            } else {
                sH[stA] = (f32x4){-1e30f, -1e30f, -1e30f, -1e30f};
                sH[stB] = (f32x4){-1e30f, -1e30f, -1e30f, -1e30f};
                sL[stA] = (f32x4){-1e30f, -1e30f, -1e30f, -1e30f};
                sL[stB] = (f32x4){-1e30f, -1e30f, -1e30f, -1e30f};
            }
        }

        // ---- causal masks ----
        if (kb + 127 > q0H) {
#pragma unroll
            for (int st = 0; st < 8; ++st) {
                if (st < nsubH) {
                    const int key = kb + st * 16 + n16;
#pragma unroll
                    for (int r = 0; r < 4; ++r)
                        if (key > q0H + quad * 4 + r) sH[st][r] = -1e30f;
                }
            }
        }
        if (lact && (kb + 127 > q0L)) {
#pragma unroll
            for (int st = 0; st < 8; ++st) {
                if (st < nsubL) {
                    const int key = kb + st * 16 + n16;
#pragma unroll
                    for (int r = 0; r < 4; ++r)
                        if (key > q0L + quad * 4 + r) sL[st][r] = -1e30f;
                }
            }
        }

        // ---- softmax H ----
        {
            float t0 = sH[0][0], t1 = sH[0][1], t2 = sH[0][2], t3 = sH[0][3];
#pragma unroll
            for (int st = 1; st < 8; ++st) {
                t0 = fmaxf(t0, sH[st][0]); t1 = fmaxf(t1, sH[st][1]);
                t2 = fmaxf(t2, sH[st][2]); t3 = fmaxf(t3, sH[st][3]);
            }
            t0 = dpp_max16(t0); t1 = dpp_max16(t1);
            t2 = dpp_max16(t2); t3 = dpp_max16(t3);
            const float n0 = fmaxf(mH0, t0), n1 = fmaxf(mH1, t1);
            const float n2 = fmaxf(mH2, t2), n3 = fmaxf(mH3, t3);
            const float a0 = __expf(mH0 - n0), a1 = __expf(mH1 - n1);
            const float a2 = __expf(mH2 - n2), a3 = __expf(mH3 - n3);
            mH0 = n0; mH1 = n1; mH2 = n2; mH3 = n3;
            float p0s = 0.f, p1s = 0.f, p2s = 0.f, p3s = 0.f;
            const int stmax = 2 * nchainH;
#pragma unroll
            for (int st = 0; st < 8; ++st) {
                if (st < stmax) {
                    float p0 = 0.f, p1 = 0.f, p2 = 0.f, p3 = 0.f;
                    if (st < nsubH) {
                        p0 = __expf(sH[st][0] - n0);
                        p1 = __expf(sH[st][1] - n1);
                        p2 = __expf(sH[st][2] - n2);
                        p3 = __expf(sH[st][3] - n3);
                        p0s += p0; p1s += p1; p2s += p2; p3s += p3;
                    }
                    const int col = st * 16 + n16;
                    sPw[(quad * 4 + 0) * 136 + col] = f2bf(p0);
                    sPw[(quad * 4 + 1) * 136 + col] = f2bf(p1);
                    sPw[(quad * 4 + 2) * 136 + col] = f2bf(p2);
                    sPw[(quad * 4 + 3) * 136 + col] = f2bf(p3);
                }
            }
            p0s = dpp_sum16(p0s); p1s = dpp_sum16(p1s);
            p2s = dpp_sum16(p2s); p3s = dpp_sum16(p3s);
            lH0 = lH0 * a0 + p0s; lH1 = lH1 * a1 + p1s;
            lH2 = lH2 * a2 + p2s; lH3 = lH3 * a3 + p3s;
#pragma unroll
            for (int nt = 0; nt < 4; ++nt) {
                oH[nt][0] *= a0; oH[nt][1] *= a1;
                oH[nt][2] *= a2; oH[nt][3] *= a3;
            }
        }

        // ---- softmax L (only when prefix-active) ----
        if (lact) {
            float t0 = sL[0][0], t1 = sL[0][1], t2 = sL[0][2], t3 = sL[0][3];
#pragma unroll
            for (int st = 1; st < 8; ++st) {
                t0 = fmaxf(t0, sL[st][0]); t1 = fmaxf(t1, sL[st][1]);
                t2 = fmaxf(t2, sL[st][2]); t3 = fmaxf(t3, sL[st][3]);
            }
            t0 = dpp_max16(t0); t1 = dpp_max16(t1);
            t2 = dpp_max16(t2); t3 = dpp_max16(t3);
            const float n0 = fmaxf(mL0, t0), n1 = fmaxf(mL1, t1);
            const float n2 = fmaxf(mL2, t2), n3 = fmaxf(mL3, t3);
            const float a0 = __expf(mL0 - n0), a1 = __expf(mL1 - n1);
            const float a2 = __expf(mL2 - n2), a3 = __expf(mL3 - n3);
            mL0 = n0; mL1 = n1; mL2 = n2; mL3 = n3;
            float p0s = 0.f, p1s = 0.f, p2s = 0.f, p3s = 0.f;
            const int stmax = 2 * nchainL;
#pragma unroll
            for (int st = 0; st < 8; ++st) {
                if (st < stmax) {
                    float p0 = 0.f, p1 = 0.f, p2 = 0.f, p3 = 0.f;
                    if (st < nsubL) {
                        p0 = __expf(sL[st][0] - n0);
                        p1 = __expf(sL[st][1] - n1);
                        p2 = __expf(sL[st][2] - n2);
                        p3 = __expf(sL[st][3] - n3);
                        p0s += p0; p1s += p1; p2s += p2; p3s += p3;
                    }
                    const int col = st * 16 + n16;
                    sPLw[(quad * 4 + 0) * 136 + col] = f2bf(p0);
                    sPLw[(quad * 4 + 1) * 136 + col] = f2bf(p1);
                    sPLw[(quad * 4 + 2) * 136 + col] = f2bf(p2);
                    sPLw[(quad * 4 + 3) * 136 + col] = f2bf(p3);
                }
            }
            p0s = dpp_sum16(p0s); p1s = dpp_sum16(p1s);
            p2s = dpp_sum16(p2s); p3s = dpp_sum16(p3s);
            lL0 = lL0 * a0 + p0s; lL1 = lL1 * a1 + p1s;
            lL2 = lL2 * a2 + p2s; lL3 = lL3 * a3 + p3s;
#pragma unroll
            for (int nt = 0; nt < 4; ++nt) {
                oL[nt][0] *= a0; oL[nt][1] *= a1;
                oL[nt][2] *= a2; oL[nt][3] *= a3;
            }
        }

        // ---- PV: V frags loaded ONCE, feed both tiles ----
#pragma unroll
        for (int ch = 0; ch < 4; ++ch) {
            if (ch < nchainH) {
                const size_t cbase =
                    (((size_t)(b * 64 + (kb >> 5) + ch)) * 4) << 9;
                short8 v0 = ld8(Vf + cbase + (0 << 9) + lane * 8);
                short8 v1 = ld8(Vf + cbase + (1 << 9) + lane * 8);
                short8 v2 = ld8(Vf + cbase + (2 << 9) + lane * 8);
                short8 v3 = ld8(Vf + cbase + (3 << 9) + lane * 8);
                if (ch < nchainL) {
                    short8 pl = ld8(&sPLw[n16 * 136 + ch * 32 + quad * 8]);
                    oL[0] = MFMA(pl, v0, oL[0]);
                    oL[1] = MFMA(pl, v1, oL[1]);
                    oL[2] = MFMA(pl, v2, oL[2]);
                    oL[3] = MFMA(pl, v3, oL[3]);
                }
                short8 ph = ld8(&sPw[n16 * 136 + ch * 32 + quad * 8]);
                oH[0] = MFMA(ph, v0, oH[0]);
                oH[1] = MFMA(ph, v1, oH[1]);
                oH[2] = MFMA(ph, v2, oH[2]);
                oH[3] = MFMA(ph, v3, oH[3]);
            }
        }
    }

    // ---- epilogue: combine + store tile L, then tile H ----
    const int row  = t >> 4;
    const int col4 = (t & 15) * 4;
#pragma unroll
    for (int tile = 0; tile < 2; ++tile) {
        const f32x4* oo = tile ? oH : oL;
#pragma unroll
        for (int nt = 0; nt < 4; ++nt)
#pragma unroll
            for (int r = 0; r < 4; ++r)
                sOw[(quad * 4 + r) * 68 + nt * 16 + n16] = oo[nt][r];
        if (n16 == 0) {
            if (tile) {
                sMl[w][quad * 4 + 0][0] = mH0; sMl[w][quad * 4 + 0][1] = lH0;
                sMl[w][quad * 4 + 1][0] = mH1; sMl[w][quad * 4 + 1][1] = lH1;
                sMl[w][quad * 4 + 2][0] = mH2; sMl[w][quad * 4 + 2][1] = lH2;
                sMl[w][quad * 4 + 3][0] = mH3; sMl[w][quad * 4 + 3][1] = lH3;
            } else {
                sMl[w][quad * 4 + 0][0] = mL0; sMl[w][quad * 4 + 0][1] = lL0;
                sMl[w][quad * 4 + 1][0] = mL1; sMl[w][quad * 4 + 1][1] = lL1;
                sMl[w][quad * 4 + 2][0] = mL2; sMl[w][quad * 4 + 2][1] = lL2;
                sMl[w][quad * 4 + 3][0] = mL3; sMl[w][quad * 4 + 3][1] = lL3;
            }
        }
        __syncthreads();
        {
            float M = fmaxf(fmaxf(sMl[0][row][0], sMl[1][row][0]),
                            fmaxf(sMl[2][row][0], sMl[3][row][0]));
            float L = 0.f;
            float ox = 0.f, oy = 0.f, oz = 0.f, ow = 0.f;
#pragma unroll
            for (int wv = 0; wv < 4; ++wv) {
                const float ew = __expf(sMl[wv][row][0] - M);
                L += ew * sMl[wv][row][1];
                const float* op = (const float*)scratch[wv] + row * 68 + col4;
                ox += ew * op[0]; oy += ew * op[1]; oz += ew * op[2]; ow += ew * op[3];
            }
            const float inv = 1.0f / L;
            const int q0 = tile ? q0H : q0L;
            float4 res = make_float4(ox * inv, oy * inv, oz * inv, ow * inv);
            *(float4*)(O + ((size_t)(boff + q0 + row)) * DIM + col4) = res;
        }
        __syncthreads();
    }
}

extern "C" void kernel_launch(void* const* d_in, const int* in_sizes, int n_in,
                              void* d_out, int out_size, void* d_ws, size_t ws_size,
                              hipStream_t stream) {
    const float* q = (const float*)d_in[0];
    const float* k = (const float*)d_in[1];
    const float* v = (const float*)d_in[2];
    float* out = (float*)d_out;

    unsigned short* Qh = (unsigned short*)d_ws;
    unsigned short* Ql = Qh + NEL;
    unsigned short* Kh = Ql + NEL;
    unsigned short* Kl = Kh + NEL;
    unsigned short* Vf = Kl + NEL;   // 10 MB total in d_ws

    prep<<<dim3(2048 + 256), dim3(256), 0, stream>>>(q, k, v, Qh, Ql, Kh, Kl, Vf);
    attn_main<<<dim3(512), dim3(256), 0, stream>>>(Qh, Ql, Kh, Kl, Vf, out);
}